// Round 4
// baseline (198.063 us; speedup 1.0000x reference)
//
#include <hip/hip_runtime.h>

// WeightedAggEdge: node_feat = h@Wn^T; per-edge segment-softmax attention
// over fc_e(e) grouped by src node; outputs (node_feat, gamma * e_w).
//
// Algebraic restructure:
//   logit a_i = dot(e_i, v) + s_n[src_i],  v = We^T @ Wa[:,0:64],
//   s_n[n] = dot(Wa[:,64:128], node_feat[n])
//   gamma_i = exp(lr_i) / denom[src_i]  (shift-invariant, no segment-max pass)
//   node_feat and e_weighted via bf16 16x16x32 MFMA (threshold 1.08e-1)
// Round 4: k2 spills e as bf16 (102 MB, L3-resident) -> k4 reads half the
// bytes with zero convert VALU; nt-stores on outputs to protect L3.

constexpr int kNodes   = 50000;
constexpr int kEdges   = 800000;
constexpr int kNodeIn  = 128;
constexpr int kNodeOut = 64;
constexpr int kEdgeIn  = 64;
constexpr int kEdgeOut = 64;
#define NEG_SLOPE 0.01f

typedef __attribute__((ext_vector_type(8))) short short8;   // 8 bf16 = 4 VGPRs
typedef __attribute__((ext_vector_type(4))) float f32x4;

// ws layout (float index):
//   [0, 64)              v = We^T @ Wa_e
//   [64, 50064)          s_n
//   [50064, 100064)      denom
//   [100064, 900064)     ex
//   [900064, 902112)     We_bf16 (4096 shorts)
//   [902112, 906208)     Wn_bf16 (8192 shorts)
//   [906240, +25.6M)     e_bf16  (kEdges*64 shorts = 102.4 MB)
constexpr int kOffV     = 0;
constexpr int kOffSn    = 64;
constexpr int kOffDenom = 50064;
constexpr int kOffEx    = 100064;
constexpr int kOffWeB   = 900064;
constexpr int kOffWnB   = 902112;
constexpr int kOffEbf   = 906240;

__device__ inline short f2bf(float x) {
    union { float f; unsigned u; } v; v.f = x;
    unsigned r = v.u + 0x7FFFu + ((v.u >> 16) & 1u);  // RNE
    return (short)(r >> 16);
}

__global__ void k0_prep(const float* __restrict__ We, const float* __restrict__ Wn,
                        const float* __restrict__ Wa,
                        float* __restrict__ v, short* __restrict__ Web,
                        short* __restrict__ Wnb) {
    int t = threadIdx.x;
    if (t < kEdgeIn) {
        float acc = 0.f;
        #pragma unroll
        for (int c = 0; c < kEdgeOut; ++c) acc = fmaf(Wa[c], We[c * kEdgeIn + t], acc);
        v[t] = acc;
    }
    #pragma unroll
    for (int i = 0; i < (kEdgeOut * kEdgeIn) / 256; ++i)
        Web[i * 256 + t] = f2bf(We[i * 256 + t]);
    #pragma unroll
    for (int i = 0; i < (kNodeOut * kNodeIn) / 256; ++i)
        Wnb[i * 256 + t] = f2bf(Wn[i * 256 + t]);
}

// node_feat = h @ Wn^T via bf16 MFMA; one wave = 16 nodes.
// Also: s_n[n] = dot(Wa[64:128], node_feat[n]) via 16-lane shfl reduce; denom init.
__global__ __launch_bounds__(256) void k1_mfma(
    const float* __restrict__ h, const short* __restrict__ Wnb,
    const float* __restrict__ Wa, float* __restrict__ node_feat,
    float* __restrict__ s_n, float* __restrict__ denom) {
    const int lane = threadIdx.x & 63;
    const int l15  = lane & 15;
    const int lhi  = lane >> 4;
    const int n0   = blockIdx.x * 64 + (threadIdx.x >> 6) * 16;

    int gid = blockIdx.x * 256 + threadIdx.x;
    if (gid < kNodes) denom[gid] = 0.f;

    short8 Bf[4][4];
    #pragma unroll
    for (int kt = 0; kt < 4; ++kt)
        #pragma unroll
        for (int ct = 0; ct < 4; ++ct)
            Bf[kt][ct] = *reinterpret_cast<const short8*>(
                Wnb + (ct * 16 + l15) * kNodeIn + kt * 32 + lhi * 8);

    const int  arow   = n0 + l15;
    const bool avalid = arow < kNodes;
    const float* hrow = h + (size_t)arow * kNodeIn;

    f32x4 acc[4];
    #pragma unroll
    for (int ct = 0; ct < 4; ++ct) acc[ct] = (f32x4)(0.f);

    #pragma unroll
    for (int kt = 0; kt < 4; ++kt) {
        short8 af;
        if (avalid) {
            float4 t0 = *reinterpret_cast<const float4*>(hrow + kt * 32 + lhi * 8);
            float4 t1 = *reinterpret_cast<const float4*>(hrow + kt * 32 + lhi * 8 + 4);
            af[0] = f2bf(t0.x); af[1] = f2bf(t0.y); af[2] = f2bf(t0.z); af[3] = f2bf(t0.w);
            af[4] = f2bf(t1.x); af[5] = f2bf(t1.y); af[6] = f2bf(t1.z); af[7] = f2bf(t1.w);
        } else {
            #pragma unroll
            for (int j = 0; j < 8; ++j) af[j] = 0;
        }
        #pragma unroll
        for (int ct = 0; ct < 4; ++ct)
            acc[ct] = __builtin_amdgcn_mfma_f32_16x16x32_bf16(af, Bf[kt][ct], acc[ct], 0, 0, 0);
    }

    float wa[4];
    #pragma unroll
    for (int ct = 0; ct < 4; ++ct) wa[ct] = Wa[64 + ct * 16 + l15];

    #pragma unroll
    for (int reg = 0; reg < 4; ++reg) {
        int r = n0 + lhi * 4 + reg;
        bool rv = r < kNodes;
        float part = 0.f;
        #pragma unroll
        for (int ct = 0; ct < 4; ++ct) part = fmaf(wa[ct], acc[ct][reg], part);
        if (rv) {
            #pragma unroll
            for (int ct = 0; ct < 4; ++ct)
                __builtin_nontemporal_store(acc[ct][reg],
                    node_feat + (size_t)r * kNodeOut + ct * 16 + l15);
        }
        part += __shfl_xor(part, 1, 64);
        part += __shfl_xor(part, 2, 64);
        part += __shfl_xor(part, 4, 64);
        part += __shfl_xor(part, 8, 64);
        if (rv && l15 == 0) s_n[r] = part;
    }
}

// logits + exp + denom atomics; also spill e as bf16 (row-major) for k4.
__global__ __launch_bounds__(256) void k2_logits(
    const float* __restrict__ e, const int* __restrict__ src,
    const float* __restrict__ v, const float* __restrict__ s_n,
    float* __restrict__ denom, float* __restrict__ ex,
    short* __restrict__ ebf) {
    int i = blockIdx.x * 256 + threadIdx.x;
    if (i >= kEdges) return;
    const float4* e4 = reinterpret_cast<const float4*>(e + (size_t)i * kEdgeIn);
    short8 row[8];
    float av = 0.f;
    #pragma unroll
    for (int q = 0; q < kEdgeIn / 4; ++q) {
        float4 t = e4[q];
        av = fmaf(t.x, v[4 * q],     av);
        av = fmaf(t.y, v[4 * q + 1], av);
        av = fmaf(t.z, v[4 * q + 2], av);
        av = fmaf(t.w, v[4 * q + 3], av);
        row[q >> 1][(q & 1) * 4 + 0] = f2bf(t.x);
        row[q >> 1][(q & 1) * 4 + 1] = f2bf(t.y);
        row[q >> 1][(q & 1) * 4 + 2] = f2bf(t.z);
        row[q >> 1][(q & 1) * 4 + 3] = f2bf(t.w);
    }
    short8* dst = reinterpret_cast<short8*>(ebf + (size_t)i * kEdgeIn);
    #pragma unroll
    for (int j = 0; j < 8; ++j) dst[j] = row[j];

    int s = src[i];
    float a = av + s_n[s];
    float lr = (a >= 0.f) ? a : NEG_SLOPE * a;
    float xe = __expf(lr);
    ex[i] = xe;
    atomicAdd(denom + s, xe);
}

// e_weighted = (ex/denom[src]) * (e @ We^T); A-fragments read directly as bf16.
__global__ __launch_bounds__(256) void k4_mfma(
    const short* __restrict__ ebf, const short* __restrict__ Web,
    const int* __restrict__ src, const float* __restrict__ denom,
    const float* __restrict__ ex, float* __restrict__ oute) {
    const int wave = threadIdx.x >> 6;
    const int lane = threadIdx.x & 63;
    const int l15  = lane & 15;
    const int lhi  = lane >> 4;
    const long base = (long)blockIdx.x * 256 + wave * 64;  // first edge row

    short8 Bf[2][4];
    #pragma unroll
    for (int kt = 0; kt < 2; ++kt)
        #pragma unroll
        for (int ct = 0; ct < 4; ++ct)
            Bf[kt][ct] = *reinterpret_cast<const short8*>(
                Web + (ct * 16 + l15) * kEdgeIn + kt * 32 + lhi * 8);

    f32x4 acc[4][4];
    #pragma unroll
    for (int m = 0; m < 4; ++m)
        #pragma unroll
        for (int n = 0; n < 4; ++n) acc[m][n] = (f32x4)(0.f);

    #pragma unroll
    for (int m = 0; m < 4; ++m) {
        const short* erow = ebf + (base + m * 16 + l15) * kEdgeIn;
        #pragma unroll
        for (int kt = 0; kt < 2; ++kt) {
            short8 af = *reinterpret_cast<const short8*>(erow + kt * 32 + lhi * 8);
            #pragma unroll
            for (int ct = 0; ct < 4; ++ct)
                acc[m][ct] = __builtin_amdgcn_mfma_f32_16x16x32_bf16(
                    af, Bf[kt][ct], acc[m][ct], 0, 0, 0);
        }
    }

    // Epilogue: D col = ct*16+l15, row = lhi*4 + reg. gamma = ex * rcp(denom[src]).
    #pragma unroll
    for (int m = 0; m < 4; ++m) {
        const long r0 = base + m * 16 + lhi * 4;
        float4 exv = *reinterpret_cast<const float4*>(ex + r0);
        int4   sv  = *reinterpret_cast<const int4*>(src + r0);
        float ga[4];
        ga[0] = exv.x * __builtin_amdgcn_rcpf(denom[sv.x]);
        ga[1] = exv.y * __builtin_amdgcn_rcpf(denom[sv.y]);
        ga[2] = exv.z * __builtin_amdgcn_rcpf(denom[sv.z]);
        ga[3] = exv.w * __builtin_amdgcn_rcpf(denom[sv.w]);
        #pragma unroll
        for (int reg = 0; reg < 4; ++reg) {
            float gv = ga[reg];
            #pragma unroll
            for (int ct = 0; ct < 4; ++ct)
                __builtin_nontemporal_store(acc[m][ct][reg] * gv,
                    oute + (r0 + reg) * kEdgeOut + ct * 16 + l15);
        }
    }
}

extern "C" void kernel_launch(void* const* d_in, const int* in_sizes, int n_in,
                              void* d_out, int out_size, void* d_ws, size_t ws_size,
                              hipStream_t stream) {
    const float* h   = (const float*)d_in[0];
    const float* e   = (const float*)d_in[1];
    const float* Wn  = (const float*)d_in[2];
    const float* We  = (const float*)d_in[3];
    const float* Wa  = (const float*)d_in[4];
    const int*   src = (const int*)d_in[5];

    float* node_feat = (float*)d_out;
    float* oute      = (float*)d_out + (size_t)kNodes * kNodeOut;

    float* ws    = (float*)d_ws;
    float* v     = ws + kOffV;
    float* s_n   = ws + kOffSn;
    float* denom = ws + kOffDenom;
    float* ex    = ws + kOffEx;
    short* Web   = (short*)(ws + kOffWeB);
    short* Wnb   = (short*)(ws + kOffWnB);
    short* ebf   = (short*)(ws + kOffEbf);

    k0_prep<<<1, 256, 0, stream>>>(We, Wn, Wa, v, Web, Wnb);
    k1_mfma<<<(kNodes + 63) / 64, 256, 0, stream>>>(h, Wnb, Wa, node_feat, s_n, denom);
    k2_logits<<<kEdges / 256, 256, 0, stream>>>(e, src, v, s_n, denom, ex, ebf);
    k4_mfma<<<kEdges / 256, 256, 0, stream>>>(ebf, Web, src, denom, ex, oute);
}

// Round 5
// 183.442 us; speedup vs baseline: 1.0797x; 1.0797x over previous
//
#include <hip/hip_runtime.h>

// WeightedAggEdge: node_feat = h@Wn^T; per-edge segment-softmax attention
// over fc_e(e) grouped by src node; outputs (node_feat, gamma * e_w).
//
// Algebraic restructure:
//   logit a_i = dot(e_i, v) + s_n[src_i],  v = We^T @ Wa[:,0:64],
//   s_n[n] = dot(Wa[:,64:128], node_feat[n])
//   gamma_i = exp(lr_i) / denom[src_i]  (shift-invariant, no segment-max pass)
//   node_feat and e_weighted via bf16 16x16x32 MFMA (threshold 1.08e-1)
// Round 5: split k2 into (a) kconv — coalesced stream e->ebf + av dot, and
// (b) k2b — tiny per-edge exp/atomic pass. Fixes the 128B-stride-per-lane
// read pattern and separates atomics from the streaming kernel.

constexpr int kNodes   = 50000;
constexpr int kEdges   = 800000;
constexpr int kNodeIn  = 128;
constexpr int kNodeOut = 64;
constexpr int kEdgeIn  = 64;
constexpr int kEdgeOut = 64;
#define NEG_SLOPE 0.01f

typedef __attribute__((ext_vector_type(8))) short short8;   // 8 bf16 = 4 VGPRs
typedef __attribute__((ext_vector_type(4))) short short4v;  // 4 bf16 = 8 B
typedef __attribute__((ext_vector_type(4))) float f32x4;

// ws layout (float index):
//   [0, 64)              v = We^T @ Wa_e
//   [64, 50064)          s_n
//   [50064, 100064)      denom
//   [100064, 900064)     av / ex (aliased: k2b reads av[i], writes ex[i])
//   [900064, 902112)     We_bf16 (4096 shorts)
//   [902112, 906208)     Wn_bf16 (8192 shorts)
//   [906240, +25.6M)     e_bf16  (kEdges*64 shorts = 102.4 MB)
constexpr int kOffV     = 0;
constexpr int kOffSn    = 64;
constexpr int kOffDenom = 50064;
constexpr int kOffEx    = 100064;
constexpr int kOffWeB   = 900064;
constexpr int kOffWnB   = 902112;
constexpr int kOffEbf   = 906240;

__device__ inline short f2bf(float x) {
    union { float f; unsigned u; } v; v.f = x;
    unsigned r = v.u + 0x7FFFu + ((v.u >> 16) & 1u);  // RNE
    return (short)(r >> 16);
}

__global__ void k0_prep(const float* __restrict__ We, const float* __restrict__ Wn,
                        const float* __restrict__ Wa,
                        float* __restrict__ v, short* __restrict__ Web,
                        short* __restrict__ Wnb) {
    int t = threadIdx.x;
    if (t < kEdgeIn) {
        float acc = 0.f;
        #pragma unroll
        for (int c = 0; c < kEdgeOut; ++c) acc = fmaf(Wa[c], We[c * kEdgeIn + t], acc);
        v[t] = acc;
    }
    #pragma unroll
    for (int i = 0; i < (kEdgeOut * kEdgeIn) / 256; ++i)
        Web[i * 256 + t] = f2bf(We[i * 256 + t]);
    #pragma unroll
    for (int i = 0; i < (kNodeOut * kNodeIn) / 256; ++i)
        Wnb[i * 256 + t] = f2bf(Wn[i * 256 + t]);
}

// node_feat = h @ Wn^T via bf16 MFMA; one wave = 16 nodes.
// Also: s_n[n] = dot(Wa[64:128], node_feat[n]) via 16-lane shfl reduce; denom init.
__global__ __launch_bounds__(256) void k1_mfma(
    const float* __restrict__ h, const short* __restrict__ Wnb,
    const float* __restrict__ Wa, float* __restrict__ node_feat,
    float* __restrict__ s_n, float* __restrict__ denom) {
    const int lane = threadIdx.x & 63;
    const int l15  = lane & 15;
    const int lhi  = lane >> 4;
    const int n0   = blockIdx.x * 64 + (threadIdx.x >> 6) * 16;

    int gid = blockIdx.x * 256 + threadIdx.x;
    if (gid < kNodes) denom[gid] = 0.f;

    short8 Bf[4][4];
    #pragma unroll
    for (int kt = 0; kt < 4; ++kt)
        #pragma unroll
        for (int ct = 0; ct < 4; ++ct)
            Bf[kt][ct] = *reinterpret_cast<const short8*>(
                Wnb + (ct * 16 + l15) * kNodeIn + kt * 32 + lhi * 8);

    const int  arow   = n0 + l15;
    const bool avalid = arow < kNodes;
    const float* hrow = h + (size_t)arow * kNodeIn;

    f32x4 acc[4];
    #pragma unroll
    for (int ct = 0; ct < 4; ++ct) acc[ct] = (f32x4)(0.f);

    #pragma unroll
    for (int kt = 0; kt < 4; ++kt) {
        short8 af;
        if (avalid) {
            float4 t0 = *reinterpret_cast<const float4*>(hrow + kt * 32 + lhi * 8);
            float4 t1 = *reinterpret_cast<const float4*>(hrow + kt * 32 + lhi * 8 + 4);
            af[0] = f2bf(t0.x); af[1] = f2bf(t0.y); af[2] = f2bf(t0.z); af[3] = f2bf(t0.w);
            af[4] = f2bf(t1.x); af[5] = f2bf(t1.y); af[6] = f2bf(t1.z); af[7] = f2bf(t1.w);
        } else {
            #pragma unroll
            for (int j = 0; j < 8; ++j) af[j] = 0;
        }
        #pragma unroll
        for (int ct = 0; ct < 4; ++ct)
            acc[ct] = __builtin_amdgcn_mfma_f32_16x16x32_bf16(af, Bf[kt][ct], acc[ct], 0, 0, 0);
    }

    float wa[4];
    #pragma unroll
    for (int ct = 0; ct < 4; ++ct) wa[ct] = Wa[64 + ct * 16 + l15];

    #pragma unroll
    for (int reg = 0; reg < 4; ++reg) {
        int r = n0 + lhi * 4 + reg;
        bool rv = r < kNodes;
        float part = 0.f;
        #pragma unroll
        for (int ct = 0; ct < 4; ++ct) part = fmaf(wa[ct], acc[ct][reg], part);
        if (rv) {
            #pragma unroll
            for (int ct = 0; ct < 4; ++ct)
                __builtin_nontemporal_store(acc[ct][reg],
                    node_feat + (size_t)r * kNodeOut + ct * 16 + l15);
        }
        part += __shfl_xor(part, 1, 64);
        part += __shfl_xor(part, 2, 64);
        part += __shfl_xor(part, 4, 64);
        part += __shfl_xor(part, 8, 64);
        if (rv && l15 == 0) s_n[r] = part;
    }
}

// Coalesced streaming pass over e: 64 rows per block (4 iters x 16 rows).
// Thread t handles float4 #(t&15) of row (base + iter*16 + (t>>4)):
//   - partial dot with v -> 16-lane shfl reduce -> av[row]
//   - bf16 convert -> 8B store to ebf (contiguous per 16-lane group)
__global__ __launch_bounds__(256) void kconv(
    const float* __restrict__ e, const float* __restrict__ v,
    short* __restrict__ ebf, float* __restrict__ av) {
    const int t   = threadIdx.x;
    const int q   = t & 15;         // float4 index within row
    const int rlo = t >> 4;         // row within 16-row group
    const long base = (long)blockIdx.x * 64;

    float4 vv = reinterpret_cast<const float4*>(v)[q];

    #pragma unroll
    for (int it = 0; it < 4; ++it) {
        long r = base + it * 16 + rlo;
        float4 d = reinterpret_cast<const float4*>(e + r * kEdgeIn)[q];
        float part = d.x * vv.x + d.y * vv.y + d.z * vv.z + d.w * vv.w;
        part += __shfl_xor(part, 1, 64);
        part += __shfl_xor(part, 2, 64);
        part += __shfl_xor(part, 4, 64);
        part += __shfl_xor(part, 8, 64);
        short4v o;
        o[0] = f2bf(d.x); o[1] = f2bf(d.y); o[2] = f2bf(d.z); o[3] = f2bf(d.w);
        *reinterpret_cast<short4v*>(ebf + r * kEdgeIn + q * 4) = o;
        if (q == 0) av[r] = part;
    }
}

// Per-edge logits: a = av[i] + s_n[src]; ex = exp(leaky(a)); denom atomic.
// av and ex alias (in-place overwrite by the same thread).
__global__ __launch_bounds__(256) void k2b(
    const int* __restrict__ src, const float* __restrict__ s_n,
    float* __restrict__ denom, float* __restrict__ ex) {
    int i = blockIdx.x * 256 + threadIdx.x;
    if (i >= kEdges) return;
    int s = src[i];
    float a = ex[i] + s_n[s];
    float lr = (a >= 0.f) ? a : NEG_SLOPE * a;
    float xe = __expf(lr);
    ex[i] = xe;
    atomicAdd(denom + s, xe);
}

// e_weighted = (ex/denom[src]) * (e @ We^T); A-fragments read directly as bf16.
__global__ __launch_bounds__(256) void k4_mfma(
    const short* __restrict__ ebf, const short* __restrict__ Web,
    const int* __restrict__ src, const float* __restrict__ denom,
    const float* __restrict__ ex, float* __restrict__ oute) {
    const int wave = threadIdx.x >> 6;
    const int lane = threadIdx.x & 63;
    const int l15  = lane & 15;
    const int lhi  = lane >> 4;
    const long base = (long)blockIdx.x * 256 + wave * 64;  // first edge row

    short8 Bf[2][4];
    #pragma unroll
    for (int kt = 0; kt < 2; ++kt)
        #pragma unroll
        for (int ct = 0; ct < 4; ++ct)
            Bf[kt][ct] = *reinterpret_cast<const short8*>(
                Web + (ct * 16 + l15) * kEdgeIn + kt * 32 + lhi * 8);

    f32x4 acc[4][4];
    #pragma unroll
    for (int m = 0; m < 4; ++m)
        #pragma unroll
        for (int n = 0; n < 4; ++n) acc[m][n] = (f32x4)(0.f);

    #pragma unroll
    for (int m = 0; m < 4; ++m) {
        const short* erow = ebf + (base + m * 16 + l15) * kEdgeIn;
        #pragma unroll
        for (int kt = 0; kt < 2; ++kt) {
            short8 af = *reinterpret_cast<const short8*>(erow + kt * 32 + lhi * 8);
            #pragma unroll
            for (int ct = 0; ct < 4; ++ct)
                acc[m][ct] = __builtin_amdgcn_mfma_f32_16x16x32_bf16(
                    af, Bf[kt][ct], acc[m][ct], 0, 0, 0);
        }
    }

    // Epilogue: D col = ct*16+l15, row = lhi*4 + reg. gamma = ex * rcp(denom[src]).
    #pragma unroll
    for (int m = 0; m < 4; ++m) {
        const long r0 = base + m * 16 + lhi * 4;
        float4 exv = *reinterpret_cast<const float4*>(ex + r0);
        int4   sv  = *reinterpret_cast<const int4*>(src + r0);
        float ga[4];
        ga[0] = exv.x * __builtin_amdgcn_rcpf(denom[sv.x]);
        ga[1] = exv.y * __builtin_amdgcn_rcpf(denom[sv.y]);
        ga[2] = exv.z * __builtin_amdgcn_rcpf(denom[sv.z]);
        ga[3] = exv.w * __builtin_amdgcn_rcpf(denom[sv.w]);
        #pragma unroll
        for (int reg = 0; reg < 4; ++reg) {
            float gv = ga[reg];
            #pragma unroll
            for (int ct = 0; ct < 4; ++ct)
                __builtin_nontemporal_store(acc[m][ct][reg] * gv,
                    oute + (r0 + reg) * kEdgeOut + ct * 16 + l15);
        }
    }
}

extern "C" void kernel_launch(void* const* d_in, const int* in_sizes, int n_in,
                              void* d_out, int out_size, void* d_ws, size_t ws_size,
                              hipStream_t stream) {
    const float* h   = (const float*)d_in[0];
    const float* e   = (const float*)d_in[1];
    const float* Wn  = (const float*)d_in[2];
    const float* We  = (const float*)d_in[3];
    const float* Wa  = (const float*)d_in[4];
    const int*   src = (const int*)d_in[5];

    float* node_feat = (float*)d_out;
    float* oute      = (float*)d_out + (size_t)kNodes * kNodeOut;

    float* ws    = (float*)d_ws;
    float* v     = ws + kOffV;
    float* s_n   = ws + kOffSn;
    float* denom = ws + kOffDenom;
    float* ex    = ws + kOffEx;   // also av
    short* Web   = (short*)(ws + kOffWeB);
    short* Wnb   = (short*)(ws + kOffWnB);
    short* ebf   = (short*)(ws + kOffEbf);

    k0_prep<<<1, 256, 0, stream>>>(We, Wn, Wa, v, Web, Wnb);
    kconv<<<kEdges / 64, 256, 0, stream>>>(e, v, ebf, ex);
    k1_mfma<<<(kNodes + 63) / 64, 256, 0, stream>>>(h, Wnb, Wa, node_feat, s_n, denom);
    k2b<<<kEdges / 256, 256, 0, stream>>>(src, s_n, denom, ex);
    k4_mfma<<<kEdges / 256, 256, 0, stream>>>(ebf, Web, src, denom, ex, oute);
}

// Round 6
// 154.341 us; speedup vs baseline: 1.2833x; 1.1886x over previous
//
#include <hip/hip_runtime.h>

// WeightedAggEdge: node_feat = h@Wn^T; per-edge segment-softmax attention
// over fc_e(e) grouped by src node; outputs (node_feat, gamma * e_w).
//
// Algebraic restructure:
//   logit a_i = dot(e_i, v) + s_n[src_i],  v = We^T @ Wa[:,0:64],
//   s_n[n] = dot(Wa[:,64:128], node_feat[n])
//   gamma_i = exp(lr_i) / denom[src_i]  (shift-invariant, no segment-max pass)
//   node_feat and e_weighted via bf16 16x16x32 MFMA (threshold 1.08e-1)
// Round 6: fuse the per-edge exp/atomic pass INTO the coalesced e-stream
// (lane q==0 of each 16-lane row group finishes the logit after the shfl
// reduce). Order: k0, k1 (s_n/denom), kconv_fused, k4. k0 parallelized.

constexpr int kNodes   = 50000;
constexpr int kEdges   = 800000;
constexpr int kNodeIn  = 128;
constexpr int kNodeOut = 64;
constexpr int kEdgeIn  = 64;
constexpr int kEdgeOut = 64;
#define NEG_SLOPE 0.01f

typedef __attribute__((ext_vector_type(8))) short short8;   // 8 bf16 = 4 VGPRs
typedef __attribute__((ext_vector_type(4))) short short4v;  // 4 bf16 = 8 B
typedef __attribute__((ext_vector_type(4))) float f32x4;

// ws layout (float index):
//   [0, 64)              v = We^T @ Wa_e
//   [64, 50064)          s_n
//   [50064, 100064)      denom
//   [100064, 900064)     ex
//   [900064, 902112)     We_bf16 (4096 shorts)
//   [902112, 906208)     Wn_bf16 (8192 shorts)
//   [906240, +25.6M)     e_bf16  (kEdges*64 shorts = 102.4 MB)
constexpr int kOffV     = 0;
constexpr int kOffSn    = 64;
constexpr int kOffDenom = 50064;
constexpr int kOffEx    = 100064;
constexpr int kOffWeB   = 900064;
constexpr int kOffWnB   = 902112;
constexpr int kOffEbf   = 906240;

__device__ inline short f2bf(float x) {
    union { float f; unsigned u; } v; v.f = x;
    unsigned r = v.u + 0x7FFFu + ((v.u >> 16) & 1u);  // RNE
    return (short)(r >> 16);
}

// 48 blocks: 0..15 convert We (4096), 16..47 convert Wn (8192); block 0 also v.
__global__ void k0_prep(const float* __restrict__ We, const float* __restrict__ Wn,
                        const float* __restrict__ Wa,
                        float* __restrict__ v, short* __restrict__ Web,
                        short* __restrict__ Wnb) {
    int b = blockIdx.x, t = threadIdx.x;
    if (b == 0 && t < kEdgeIn) {
        float acc = 0.f;
        #pragma unroll
        for (int c = 0; c < kEdgeOut; ++c) acc = fmaf(Wa[c], We[c * kEdgeIn + t], acc);
        v[t] = acc;
    }
    if (b < 16) {
        int i = b * 256 + t;
        Web[i] = f2bf(We[i]);
    } else {
        int i = (b - 16) * 256 + t;
        Wnb[i] = f2bf(Wn[i]);
    }
}

// node_feat = h @ Wn^T via bf16 MFMA; one wave = 16 nodes.
// Also: s_n[n] = dot(Wa[64:128], node_feat[n]) via 16-lane shfl reduce; denom init.
__global__ __launch_bounds__(256) void k1_mfma(
    const float* __restrict__ h, const short* __restrict__ Wnb,
    const float* __restrict__ Wa, float* __restrict__ node_feat,
    float* __restrict__ s_n, float* __restrict__ denom) {
    const int lane = threadIdx.x & 63;
    const int l15  = lane & 15;
    const int lhi  = lane >> 4;
    const int n0   = blockIdx.x * 64 + (threadIdx.x >> 6) * 16;

    int gid = blockIdx.x * 256 + threadIdx.x;
    if (gid < kNodes) denom[gid] = 0.f;

    short8 Bf[4][4];
    #pragma unroll
    for (int kt = 0; kt < 4; ++kt)
        #pragma unroll
        for (int ct = 0; ct < 4; ++ct)
            Bf[kt][ct] = *reinterpret_cast<const short8*>(
                Wnb + (ct * 16 + l15) * kNodeIn + kt * 32 + lhi * 8);

    const int  arow   = n0 + l15;
    const bool avalid = arow < kNodes;
    const float* hrow = h + (size_t)arow * kNodeIn;

    f32x4 acc[4];
    #pragma unroll
    for (int ct = 0; ct < 4; ++ct) acc[ct] = (f32x4)(0.f);

    #pragma unroll
    for (int kt = 0; kt < 4; ++kt) {
        short8 af;
        if (avalid) {
            float4 t0 = *reinterpret_cast<const float4*>(hrow + kt * 32 + lhi * 8);
            float4 t1 = *reinterpret_cast<const float4*>(hrow + kt * 32 + lhi * 8 + 4);
            af[0] = f2bf(t0.x); af[1] = f2bf(t0.y); af[2] = f2bf(t0.z); af[3] = f2bf(t0.w);
            af[4] = f2bf(t1.x); af[5] = f2bf(t1.y); af[6] = f2bf(t1.z); af[7] = f2bf(t1.w);
        } else {
            #pragma unroll
            for (int j = 0; j < 8; ++j) af[j] = 0;
        }
        #pragma unroll
        for (int ct = 0; ct < 4; ++ct)
            acc[ct] = __builtin_amdgcn_mfma_f32_16x16x32_bf16(af, Bf[kt][ct], acc[ct], 0, 0, 0);
    }

    float wa[4];
    #pragma unroll
    for (int ct = 0; ct < 4; ++ct) wa[ct] = Wa[64 + ct * 16 + l15];

    #pragma unroll
    for (int reg = 0; reg < 4; ++reg) {
        int r = n0 + lhi * 4 + reg;
        bool rv = r < kNodes;
        float part = 0.f;
        #pragma unroll
        for (int ct = 0; ct < 4; ++ct) part = fmaf(wa[ct], acc[ct][reg], part);
        if (rv) {
            #pragma unroll
            for (int ct = 0; ct < 4; ++ct)
                __builtin_nontemporal_store(acc[ct][reg],
                    node_feat + (size_t)r * kNodeOut + ct * 16 + l15);
        }
        part += __shfl_xor(part, 1, 64);
        part += __shfl_xor(part, 2, 64);
        part += __shfl_xor(part, 4, 64);
        part += __shfl_xor(part, 8, 64);
        if (rv && l15 == 0) s_n[r] = part;
    }
}

// Coalesced streaming pass over e: 64 rows per block (4 iters x 16 rows).
// Thread t handles float4 #(t&15) of row (base + iter*16 + (t>>4)):
//   - partial dot with v -> 16-lane shfl reduce -> full logit on lane q==0:
//     a = av + s_n[src]; ex = exp(leaky(a)); atomicAdd(denom[src])
//   - bf16 convert -> 8B store to ebf (contiguous per 16-lane group)
__global__ __launch_bounds__(256) void kconv(
    const float* __restrict__ e, const float* __restrict__ v,
    const int* __restrict__ src, const float* __restrict__ s_n,
    float* __restrict__ denom, float* __restrict__ ex,
    short* __restrict__ ebf) {
    const int t   = threadIdx.x;
    const int q   = t & 15;         // float4 index within row
    const int rlo = t >> 4;         // row within 16-row group
    const long base = (long)blockIdx.x * 64;

    float4 vv = reinterpret_cast<const float4*>(v)[q];

    #pragma unroll
    for (int it = 0; it < 4; ++it) {
        long r = base + it * 16 + rlo;
        float4 d = reinterpret_cast<const float4*>(e + r * kEdgeIn)[q];
        float part = d.x * vv.x + d.y * vv.y + d.z * vv.z + d.w * vv.w;
        part += __shfl_xor(part, 1, 64);
        part += __shfl_xor(part, 2, 64);
        part += __shfl_xor(part, 4, 64);
        part += __shfl_xor(part, 8, 64);
        short4v o;
        o[0] = f2bf(d.x); o[1] = f2bf(d.y); o[2] = f2bf(d.z); o[3] = f2bf(d.w);
        *reinterpret_cast<short4v*>(ebf + r * kEdgeIn + q * 4) = o;
        if (q == 0) {
            int s = src[r];
            float a = part + s_n[s];
            float lr = (a >= 0.f) ? a : NEG_SLOPE * a;
            float xe = __expf(lr);
            ex[r] = xe;
            atomicAdd(denom + s, xe);
        }
    }
}

// e_weighted = (ex/denom[src]) * (e @ We^T); A-fragments read directly as bf16.
__global__ __launch_bounds__(256) void k4_mfma(
    const short* __restrict__ ebf, const short* __restrict__ Web,
    const int* __restrict__ src, const float* __restrict__ denom,
    const float* __restrict__ ex, float* __restrict__ oute) {
    const int wave = threadIdx.x >> 6;
    const int lane = threadIdx.x & 63;
    const int l15  = lane & 15;
    const int lhi  = lane >> 4;
    const long base = (long)blockIdx.x * 256 + wave * 64;  // first edge row

    short8 Bf[2][4];
    #pragma unroll
    for (int kt = 0; kt < 2; ++kt)
        #pragma unroll
        for (int ct = 0; ct < 4; ++ct)
            Bf[kt][ct] = *reinterpret_cast<const short8*>(
                Web + (ct * 16 + l15) * kEdgeIn + kt * 32 + lhi * 8);

    f32x4 acc[4][4];
    #pragma unroll
    for (int m = 0; m < 4; ++m)
        #pragma unroll
        for (int n = 0; n < 4; ++n) acc[m][n] = (f32x4)(0.f);

    #pragma unroll
    for (int m = 0; m < 4; ++m) {
        const short* erow = ebf + (base + m * 16 + l15) * kEdgeIn;
        #pragma unroll
        for (int kt = 0; kt < 2; ++kt) {
            short8 af = *reinterpret_cast<const short8*>(erow + kt * 32 + lhi * 8);
            #pragma unroll
            for (int ct = 0; ct < 4; ++ct)
                acc[m][ct] = __builtin_amdgcn_mfma_f32_16x16x32_bf16(
                    af, Bf[kt][ct], acc[m][ct], 0, 0, 0);
        }
    }

    // Epilogue: D col = ct*16+l15, row = lhi*4 + reg. gamma = ex * rcp(denom[src]).
    #pragma unroll
    for (int m = 0; m < 4; ++m) {
        const long r0 = base + m * 16 + lhi * 4;
        float4 exv = *reinterpret_cast<const float4*>(ex + r0);
        int4   sv  = *reinterpret_cast<const int4*>(src + r0);
        float ga[4];
        ga[0] = exv.x * __builtin_amdgcn_rcpf(denom[sv.x]);
        ga[1] = exv.y * __builtin_amdgcn_rcpf(denom[sv.y]);
        ga[2] = exv.z * __builtin_amdgcn_rcpf(denom[sv.z]);
        ga[3] = exv.w * __builtin_amdgcn_rcpf(denom[sv.w]);
        #pragma unroll
        for (int reg = 0; reg < 4; ++reg) {
            float gv = ga[reg];
            #pragma unroll
            for (int ct = 0; ct < 4; ++ct)
                __builtin_nontemporal_store(acc[m][ct][reg] * gv,
                    oute + (r0 + reg) * kEdgeOut + ct * 16 + l15);
        }
    }
}

extern "C" void kernel_launch(void* const* d_in, const int* in_sizes, int n_in,
                              void* d_out, int out_size, void* d_ws, size_t ws_size,
                              hipStream_t stream) {
    const float* h   = (const float*)d_in[0];
    const float* e   = (const float*)d_in[1];
    const float* Wn  = (const float*)d_in[2];
    const float* We  = (const float*)d_in[3];
    const float* Wa  = (const float*)d_in[4];
    const int*   src = (const int*)d_in[5];

    float* node_feat = (float*)d_out;
    float* oute      = (float*)d_out + (size_t)kNodes * kNodeOut;

    float* ws    = (float*)d_ws;
    float* v     = ws + kOffV;
    float* s_n   = ws + kOffSn;
    float* denom = ws + kOffDenom;
    float* ex    = ws + kOffEx;
    short* Web   = (short*)(ws + kOffWeB);
    short* Wnb   = (short*)(ws + kOffWnB);
    short* ebf   = (short*)(ws + kOffEbf);

    k0_prep<<<48, 256, 0, stream>>>(We, Wn, Wa, v, Web, Wnb);
    k1_mfma<<<(kNodes + 63) / 64, 256, 0, stream>>>(h, Wnb, Wa, node_feat, s_n, denom);
    kconv<<<kEdges / 64, 256, 0, stream>>>(e, v, src, s_n, denom, ex, ebf);
    k4_mfma<<<kEdges / 256, 256, 0, stream>>>(ebf, Web, src, denom, ex, oute);
}